// Round 2
// baseline (2544.805 us; speedup 1.0000x reference)
//
#include <hip/hip_runtime.h>
#include <math.h>

#define NT 512

// ---- double (activation) region offsets, in doubles ----
#define D_YBUF 0
#define D_YCUR 64
#define D_KACC 128
#define D_H1   192
#define D_D1   320
#define D_H2   448
#define D_D2   576
#define D_FB   704     // 512
#define D_T3   1216    // 512
#define D_WMT  1728    // [8][68]
#define D_U1   2272    // [8][132]
#define D_U2   3328    // [8][132]
#define D_VSIG 4384    // 16*36
#define D_CMAT 4960    // 64
#define D_HID  5024    // 17*64
#define D_X0   6112    // 8
#define D_TOTAL 6120

// ---- float (weight) region offsets, in floats (after double region) ----
#define FW1 0          // [128][68]
#define FW2 8704       // [128][132]
#define F_TOTAL 25600

#define SMEM_BYTES (D_TOTAL * 8 + F_TOTAL * 4)

static __device__ __forceinline__ double lipswish_d(double z, double* d) {
    double s = 1.0 / (1.0 + exp(-z));
    *d = 0.909 * s * (1.0 + z * (1.0 - s));
    return 0.909 * z * s;
}

extern "C" __global__ void __launch_bounds__(NT, 2)
ncde_solve(const float* __restrict__ x,
           const float* __restrict__ ic_w1, const float* __restrict__ ic_b1,
           const float* __restrict__ ic_w2, const float* __restrict__ ic_b2,
           const float* __restrict__ ic_w3, const float* __restrict__ ic_b3,
           const float* __restrict__ vf_w1, const float* __restrict__ vf_b1,
           const float* __restrict__ vf_w2, const float* __restrict__ vf_b2,
           const float* __restrict__ vf_w3, const float* __restrict__ vf_b3,
           const float* __restrict__ ro_w,  const float* __restrict__ ro_b,
           float* __restrict__ out)
{
    extern __shared__ char smraw[];
    double* smd = reinterpret_cast<double*>(smraw);
    float*  smw = reinterpret_cast<float*>(smd + D_TOTAL);

    const int t = threadIdx.x;
    const int b = blockIdx.x;
    const float* xb = x + (size_t)b * (257 * 8);

    // ---- ic MLP (stage ic_w2 into FW2) ----
    for (int idx = t; idx < 16384; idx += NT)
        smw[FW2 + (idx >> 7) * 132 + (idx & 127)] = ic_w2[idx];
    if (t < 8) smd[D_X0 + t] = (double)xb[t];
    __syncthreads();

    if (t < 128) {
        double acc = (double)ic_b1[t];
        #pragma unroll
        for (int e = 0; e < 8; ++e) acc += (double)ic_w1[t * 8 + e] * smd[D_X0 + e];
        double d;
        smd[D_H1 + t] = lipswish_d(acc, &d);
    }
    __syncthreads();
    if (t < 128) {
        double acc = (double)ic_b2[t];
        const float* wrow = &smw[FW2 + t * 132];
        #pragma unroll
        for (int c = 0; c < 128; ++c) acc += (double)wrow[c] * smd[D_H1 + c];
        double d;
        smd[D_H2 + t] = lipswish_d(acc, &d);
    }
    __syncthreads();
    for (int idx = t; idx < 8192; idx += NT)
        smw[FW2 + (idx >> 7) * 132 + (idx & 127)] = ic_w3[idx];
    __syncthreads();
    if (t < 64) {
        double acc = (double)ic_b3[t];
        const float* wrow = &smw[FW2 + t * 132];
        #pragma unroll
        for (int c = 0; c < 128; ++c) acc += (double)wrow[c] * smd[D_H2 + c];
        smd[D_YCUR + t] = acc;
        smd[D_HID + t]  = acc;
    }
    __syncthreads();

    // ---- stage vf weights into LDS ----
    for (int idx = t; idx < 16384; idx += NT)
        smw[FW2 + (idx >> 7) * 132 + (idx & 127)] = vf_w2[idx];
    for (int idx = t; idx < 8192; idx += NT)
        smw[FW1 + (idx >> 6) * 68 + (idx & 63)] = vf_w1[idx];

    // ---- depth-2 Lyndon logsigs (double): thread w handles window w ----
    if (t < 16) {
        const float* xr = xb + t * 16 * 8;
        double cum[8], area[28], prev[8];
        #pragma unroll
        for (int i = 0; i < 8; ++i) { cum[i] = 0.0; prev[i] = (double)xr[i]; }
        #pragma unroll
        for (int p = 0; p < 28; ++p) area[p] = 0.0;
        for (int k = 1; k <= 16; ++k) {
            double dx[8];
            #pragma unroll
            for (int i = 0; i < 8; ++i) {
                double c = (double)xr[k * 8 + i];
                dx[i] = c - prev[i];
                prev[i] = c;
            }
            #pragma unroll
            for (int i = 0; i < 7; ++i) {
                #pragma unroll
                for (int j = i + 1; j < 8; ++j) {
                    int p = 7 * i - (i * (i - 1)) / 2 + (j - i - 1);
                    area[p] += 0.5 * (cum[i] * dx[j] - cum[j] * dx[i]);
                }
            }
            #pragma unroll
            for (int i = 0; i < 8; ++i) cum[i] += dx[i];
        }
        #pragma unroll
        for (int i = 0; i < 8; ++i) smd[D_VSIG + t * 36 + i] = cum[i];
        #pragma unroll
        for (int p = 0; p < 28; ++p) smd[D_VSIG + t * 36 + 8 + p] = area[p];
    }
    __syncthreads();

    // ---- vf_w3 row t resident in registers (f32, exact) ----
    float4 w3q[32];
    {
        const float4* src = reinterpret_cast<const float4*>(vf_w3) + (size_t)t * 32;
        #pragma unroll
        for (int q = 0; q < 32; ++q) w3q[q] = src[q];
    }
    const double b3t = (double)vf_b3[t];

    // ---- RK4 scan over 16 windows ----
    for (int w = 0; w < 16; ++w) {
        const double* v = &smd[D_VSIG + w * 36];
        if (t < 64) {
            int a = t >> 3, bb = t & 7;
            double cv = 0.0;
            if (a != bb) {
                int i = a < bb ? a : bb;
                int j = a < bb ? bb : a;
                int pidx = 7 * i - (i * (i - 1)) / 2 + (j - i - 1);
                double vv = v[8 + pidx];
                cv = (a > bb) ? vv : -vv;
            }
            smd[D_CMAT + t] = cv;
            smd[D_YBUF + t] = smd[D_YCUR + t];
        }
        __syncthreads();

        for (int stage = 0; stage < 4; ++stage) {
            // L1: z1 = W1*y + b1
            if (t < 128) {
                double acc = (double)vf_b1[t];
                const float* wrow = &smw[FW1 + t * 68];
                #pragma unroll
                for (int e = 0; e < 64; ++e) acc += (double)wrow[e] * smd[D_YBUF + e];
                double d;
                smd[D_H1 + t] = lipswish_d(acc, &d);
                smd[D_D1 + t] = d;
            }
            __syncthreads();
            // L2
            if (t < 128) {
                double acc = (double)vf_b2[t];
                const float* wrow = &smw[FW2 + t * 132];
                #pragma unroll
                for (int c = 0; c < 128; ++c) acc += (double)wrow[c] * smd[D_H1 + c];
                double d;
                smd[D_H2 + t] = lipswish_d(acc, &d);
                smd[D_D2 + t] = d;
            }
            __syncthreads();
            // L3 forward: F = tanh(z3), row t
            {
                double acc = b3t;
                #pragma unroll
                for (int c4 = 0; c4 < 32; ++c4) {
                    float4 wv = w3q[c4];
                    acc += (double)wv.x * smd[D_H2 + 4 * c4]
                         + (double)wv.y * smd[D_H2 + 4 * c4 + 1]
                         + (double)wv.z * smd[D_H2 + 4 * c4 + 2]
                         + (double)wv.w * smd[D_H2 + 4 * c4 + 3];
                }
                smd[D_FB + t] = tanh(acc);
            }
            __syncthreads();
            // wm[a][e] = sum_b c[a,b] * F[b,e]
            {
                int e = t >> 3, a = t & 7;
                double acc = 0.0;
                #pragma unroll
                for (int bb = 0; bb < 8; ++bb)
                    acc += smd[D_CMAT + a * 8 + bb] * smd[D_FB + bb * 64 + e];
                smd[D_WMT + a * 68 + e] = acc;
            }
            __syncthreads();
            // U1[a][r] = d1[r] * (W1 @ w_a)[r]
            {
                int r = t >> 3, a = t & 7;
                double acc0 = 0.0, acc1 = 0.0;
                const float* w1a = &smw[FW1 + r * 68];
                const float* w1b = &smw[FW1 + (r + 64) * 68];
                const double* wq = &smd[D_WMT + a * 68];
                #pragma unroll
                for (int e = 0; e < 64; ++e) {
                    double wm = wq[e];
                    acc0 += (double)w1a[e] * wm;
                    acc1 += (double)w1b[e] * wm;
                }
                smd[D_U1 + a * 132 + r]      = acc0 * smd[D_D1 + r];
                smd[D_U1 + a * 132 + r + 64] = acc1 * smd[D_D1 + r + 64];
            }
            __syncthreads();
            // U2[a][r] = d2[r] * (W2 @ U1[a])[r]
            {
                int r = t >> 3, a = t & 7;
                double acc0 = 0.0, acc1 = 0.0;
                const float* w2a = &smw[FW2 + r * 132];
                const float* w2b = &smw[FW2 + (r + 64) * 132];
                const double* uq = &smd[D_U1 + a * 132];
                #pragma unroll
                for (int c = 0; c < 128; ++c) {
                    double uv = uq[c];
                    acc0 += (double)w2a[c] * uv;
                    acc1 += (double)w2b[c] * uv;
                }
                smd[D_U2 + a * 132 + r]      = acc0 * smd[D_D2 + r];
                smd[D_U2 + a * 132 + r + 64] = acc1 * smd[D_D2 + r + 64];
            }
            __syncthreads();
            // t3[t] = (1-F^2) * (W3[t,:] @ U2[a]),  a = t>>6
            {
                int a = t >> 6;
                const double* uq = &smd[D_U2 + a * 132];
                double acc = 0.0;
                #pragma unroll
                for (int c4 = 0; c4 < 32; ++c4) {
                    float4 wv = w3q[c4];
                    acc += (double)wv.x * uq[4 * c4]
                         + (double)wv.y * uq[4 * c4 + 1]
                         + (double)wv.z * uq[4 * c4 + 2]
                         + (double)wv.w * uq[4 * c4 + 3];
                }
                double F = smd[D_FB + t];
                smd[D_T3 + t] = (1.0 - F * F) * acc;
            }
            __syncthreads();
            // g combine + RK4 glue (t<64 owns state)
            if (t < 64) {
                double g = 0.0;
                #pragma unroll
                for (int a = 0; a < 8; ++a)
                    g += v[a] * smd[D_FB + a * 64 + t] + smd[D_T3 + a * 64 + t];
                double y = smd[D_YCUR + t];
                if (stage == 0)      { smd[D_KACC + t] = g;         smd[D_YBUF + t] = y + 0.5 * g; }
                else if (stage == 1) { smd[D_KACC + t] += 2.0 * g;  smd[D_YBUF + t] = y + 0.5 * g; }
                else if (stage == 2) { smd[D_KACC + t] += 2.0 * g;  smd[D_YBUF + t] = y + g; }
                else {
                    double yn = y + (smd[D_KACC + t] + g) * (1.0 / 6.0);
                    smd[D_YCUR + t] = yn;
                    smd[D_HID + (w + 1) * 64 + t] = yn;
                }
            }
            __syncthreads();
        }
    }

    // ---- readout: out[s,o] = hidden[s,:] @ ro_w[o,:] + ro_b[o] ----
    for (int idx = t; idx < 544; idx += NT) {
        int s = idx >> 5, o = idx & 31;
        double acc = (double)ro_b[o];
        const float* wr = ro_w + o * 64;
        const double* hr = &smd[D_HID + s * 64];
        #pragma unroll
        for (int d = 0; d < 64; ++d) acc += (double)wr[d] * hr[d];
        out[(size_t)b * 544 + idx] = (float)acc;
    }
}

extern "C" void kernel_launch(void* const* d_in, const int* in_sizes, int n_in,
                              void* d_out, int out_size, void* d_ws, size_t ws_size,
                              hipStream_t stream) {
    const float* x     = (const float*)d_in[0];
    const float* ic_w1 = (const float*)d_in[1];
    const float* ic_b1 = (const float*)d_in[2];
    const float* ic_w2 = (const float*)d_in[3];
    const float* ic_b2 = (const float*)d_in[4];
    const float* ic_w3 = (const float*)d_in[5];
    const float* ic_b3 = (const float*)d_in[6];
    const float* vf_w1 = (const float*)d_in[7];
    const float* vf_b1 = (const float*)d_in[8];
    const float* vf_w2 = (const float*)d_in[9];
    const float* vf_b2 = (const float*)d_in[10];
    const float* vf_w3 = (const float*)d_in[11];
    const float* vf_b3 = (const float*)d_in[12];
    const float* ro_w  = (const float*)d_in[13];
    const float* ro_b  = (const float*)d_in[14];
    float* out = (float*)d_out;

    int B = in_sizes[0] / (257 * 8);
    size_t shmem = (size_t)SMEM_BYTES;
    hipFuncSetAttribute(reinterpret_cast<const void*>(ncde_solve),
                        hipFuncAttributeMaxDynamicSharedMemorySize, (int)shmem);
    hipLaunchKernelGGL(ncde_solve, dim3(B), dim3(NT), shmem, stream,
                       x, ic_w1, ic_b1, ic_w2, ic_b2, ic_w3, ic_b3,
                       vf_w1, vf_b1, vf_w2, vf_b2, vf_w3, vf_b3, ro_w, ro_b, out);
}

// Round 3
// 2224.156 us; speedup vs baseline: 1.1442x; 1.1442x over previous
//
#include <hip/hip_runtime.h>
#include <math.h>

#define NT 512

// ---- double (activation) region, offsets in doubles ----
#define D_YBUF 0
#define D_YCUR 64
#define D_KACC 128
#define D_H1   192
#define D_D1   320
#define D_H2   448
#define D_D2   576
#define D_FB   704     // 512
#define D_T3   1216    // 512
#define D_WMT  1728    // [8][68]
#define D_U1   2272    // [8][132]
#define D_U2   3328    // [8][132]
#define D_VSIG 4384    // [16][36]
#define D_CMAT 4960    // 64
#define D_HID  5024    // [17][64]
#define D_X0   6112    // 8
#define D_PART 6120    // [4][132]
#define D_TOTAL 6656

// ---- float region: packed-transposed weights (float2 units) ----
// FW1: 4096 float2: W1P[e2*128 + r] = (W1[r][2e2], W1[r][2e2+1])
// FW2: 8192 float2: W2P[c2*128 + r] = (W2[r][2c2], W2[r][2c2+1])
#define FW1 0
#define FW2 8192
#define F_TOTAL 24576

#define SMEM_BYTES (D_TOTAL * 8 + F_TOTAL * 4)

static __device__ __forceinline__ double lipswish_d(double z, double* d) {
    double s = 1.0 / (1.0 + exp(-z));
    *d = 0.909 * s * (1.0 + z * (1.0 - s));
    return 0.909 * z * s;
}

extern "C" __global__ void __launch_bounds__(NT, 2)
ncde_solve(const float* __restrict__ x,
           const float* __restrict__ ic_w1, const float* __restrict__ ic_b1,
           const float* __restrict__ ic_w2, const float* __restrict__ ic_b2,
           const float* __restrict__ ic_w3, const float* __restrict__ ic_b3,
           const float* __restrict__ vf_w1, const float* __restrict__ vf_b1,
           const float* __restrict__ vf_w2, const float* __restrict__ vf_b2,
           const float* __restrict__ vf_w3, const float* __restrict__ vf_b3,
           const float* __restrict__ ro_w,  const float* __restrict__ ro_b,
           float* __restrict__ out)
{
    extern __shared__ char smraw[];
    double* smd = reinterpret_cast<double*>(smraw);
    float*  smw = reinterpret_cast<float*>(smd + D_TOTAL);
    float2* W1P = reinterpret_cast<float2*>(smw + FW1);
    float2* W2P = reinterpret_cast<float2*>(smw + FW2);

    const int t = threadIdx.x;
    const int b = blockIdx.x;
    const float* xb = x + (size_t)b * (257 * 8);

    // ---- vf_w3 row t in registers ----
    float4 w3q[32];
    {
        const float4* src = reinterpret_cast<const float4*>(vf_w3) + (size_t)t * 32;
        #pragma unroll
        for (int q = 0; q < 32; ++q) w3q[q] = src[q];
    }
    const double b3t = (double)vf_b3[t];

    // ==== Phase 1: stage ic_w2 (packed into FW2), ic_w3 (packed into FW1), X0, logsigs ====
    for (int j = t; j < 8192; j += NT) {           // ic_w2: 128x128
        int c2 = j >> 7, r = j & 127;
        smw[FW2 + 2 * j]     = ic_w2[r * 128 + 2 * c2];
        smw[FW2 + 2 * j + 1] = ic_w2[r * 128 + 2 * c2 + 1];
    }
    for (int j = t; j < 4096; j += NT) {           // ic_w3: 64x128 -> P[c2*64+o]
        int c2 = j >> 6, o = j & 63;
        smw[FW1 + 2 * j]     = ic_w3[o * 128 + 2 * c2];
        smw[FW1 + 2 * j + 1] = ic_w3[o * 128 + 2 * c2 + 1];
    }
    if (t < 8) smd[D_X0 + t] = (double)xb[t];
    if (t < 16) {
        const float* xr = xb + t * 16 * 8;
        double cum[8], area[28], prev[8];
        #pragma unroll
        for (int i = 0; i < 8; ++i) { cum[i] = 0.0; prev[i] = (double)xr[i]; }
        #pragma unroll
        for (int p = 0; p < 28; ++p) area[p] = 0.0;
        for (int k = 1; k <= 16; ++k) {
            double dx[8];
            #pragma unroll
            for (int i = 0; i < 8; ++i) {
                double c = (double)xr[k * 8 + i];
                dx[i] = c - prev[i];
                prev[i] = c;
            }
            #pragma unroll
            for (int i = 0; i < 7; ++i) {
                #pragma unroll
                for (int j = i + 1; j < 8; ++j) {
                    int p = 7 * i - (i * (i - 1)) / 2 + (j - i - 1);
                    area[p] += 0.5 * (cum[i] * dx[j] - cum[j] * dx[i]);
                }
            }
            #pragma unroll
            for (int i = 0; i < 8; ++i) cum[i] += dx[i];
        }
        #pragma unroll
        for (int i = 0; i < 8; ++i) smd[D_VSIG + t * 36 + i] = cum[i];
        #pragma unroll
        for (int p = 0; p < 28; ++p) smd[D_VSIG + t * 36 + 8 + p] = area[p];
    }
    __syncthreads();

    // ==== ic MLP ====
    if (t < 128) {
        double acc = (double)ic_b1[t];
        #pragma unroll
        for (int e = 0; e < 8; ++e) acc += (double)ic_w1[t * 8 + e] * smd[D_X0 + e];
        double d;
        smd[D_H1 + t] = lipswish_d(acc, &d);
    }
    __syncthreads();
    if (t < 128) {
        double a0 = 0.0, a1 = 0.0;
        #pragma unroll
        for (int c2 = 0; c2 < 64; ++c2) {
            float2 w = W2P[c2 * 128 + t];
            double2 h = *reinterpret_cast<const double2*>(&smd[D_H1 + 2 * c2]);
            a0 += (double)w.x * h.x;
            a1 += (double)w.y * h.y;
        }
        double d;
        smd[D_H2 + t] = lipswish_d((double)ic_b2[t] + a0 + a1, &d);
    }
    __syncthreads();
    if (t < 64) {
        double a0 = 0.0, a1 = 0.0;
        #pragma unroll
        for (int c2 = 0; c2 < 64; ++c2) {
            float2 w = W1P[c2 * 64 + t];   // ic_w3 packed at stride 64
            double2 h = *reinterpret_cast<const double2*>(&smd[D_H2 + 2 * c2]);
            a0 += (double)w.x * h.x;
            a1 += (double)w.y * h.y;
        }
        double y0 = (double)ic_b3[t] + a0 + a1;
        smd[D_YCUR + t] = y0;
        smd[D_HID + t]  = y0;
    }
    __syncthreads();

    // ==== stage vf weights (packed-transposed), init CMAT(w=0) + YBUF ====
    for (int j = t; j < 4096; j += NT) {           // vf_w1: 128x64
        int e2 = j >> 7, r = j & 127;
        smw[FW1 + 2 * j]     = vf_w1[r * 64 + 2 * e2];
        smw[FW1 + 2 * j + 1] = vf_w1[r * 64 + 2 * e2 + 1];
    }
    for (int j = t; j < 8192; j += NT) {           // vf_w2: 128x128
        int c2 = j >> 7, r = j & 127;
        smw[FW2 + 2 * j]     = vf_w2[r * 128 + 2 * c2];
        smw[FW2 + 2 * j + 1] = vf_w2[r * 128 + 2 * c2 + 1];
    }
    if (t < 64) {
        int a = t >> 3, bb = t & 7;
        double cv = 0.0;
        if (a != bb) {
            int i = a < bb ? a : bb;
            int j = a < bb ? bb : a;
            int pidx = 7 * i - (i * (i - 1)) / 2 + (j - i - 1);
            double vv = smd[D_VSIG + 8 + pidx];
            cv = (a > bb) ? vv : -vv;
        }
        smd[D_CMAT + t] = cv;
        smd[D_YBUF + t] = smd[D_YCUR + t];
    }
    __syncthreads();

    // ==== RK4 scan ====
    for (int w = 0; w < 16; ++w) {
        const double* v = &smd[D_VSIG + w * 36];
        for (int stage = 0; stage < 4; ++stage) {
            // L1 split-4: o = t&127, p = t>>7, e2 in [8p, 8p+8)
            {
                int o = t & 127, p = t >> 7;
                double a0 = 0.0, a1 = 0.0;
                #pragma unroll
                for (int k = 0; k < 8; ++k) {
                    int e2 = 8 * p + k;
                    float2 wv = W1P[e2 * 128 + o];
                    double2 yv = *reinterpret_cast<const double2*>(&smd[D_YBUF + 2 * e2]);
                    a0 += (double)wv.x * yv.x;
                    a1 += (double)wv.y * yv.y;
                }
                smd[D_PART + p * 132 + o] = a0 + a1;
            }
            __syncthreads();
            if (t < 128) {
                double s = smd[D_PART + t] + smd[D_PART + 132 + t]
                         + smd[D_PART + 264 + t] + smd[D_PART + 396 + t]
                         + (double)vf_b1[t];
                double d;
                smd[D_H1 + t] = lipswish_d(s, &d);
                smd[D_D1 + t] = d;
            }
            __syncthreads();
            // L2 split-4: c2 in [16p, 16p+16)
            {
                int o = t & 127, p = t >> 7;
                double a0 = 0.0, a1 = 0.0, a2 = 0.0, a3 = 0.0;
                #pragma unroll
                for (int k = 0; k < 16; ++k) {
                    int c2 = 16 * p + k;
                    float2 wv = W2P[c2 * 128 + o];
                    double2 hv = *reinterpret_cast<const double2*>(&smd[D_H1 + 2 * c2]);
                    if (k & 1) { a2 += (double)wv.x * hv.x; a3 += (double)wv.y * hv.y; }
                    else       { a0 += (double)wv.x * hv.x; a1 += (double)wv.y * hv.y; }
                }
                smd[D_PART + p * 132 + o] = (a0 + a2) + (a1 + a3);
            }
            __syncthreads();
            if (t < 128) {
                double s = smd[D_PART + t] + smd[D_PART + 132 + t]
                         + smd[D_PART + 264 + t] + smd[D_PART + 396 + t]
                         + (double)vf_b2[t];
                double d;
                smd[D_H2 + t] = lipswish_d(s, &d);
                smd[D_D2 + t] = d;
            }
            __syncthreads();
            // L3: F = tanh(W3 h2 + b3), row t (W3 in regs)
            {
                double a0 = 0.0, a1 = 0.0, a2 = 0.0, a3 = 0.0;
                #pragma unroll
                for (int q = 0; q < 32; ++q) {
                    float4 wv = w3q[q];
                    double2 h0 = *reinterpret_cast<const double2*>(&smd[D_H2 + 4 * q]);
                    double2 h1 = *reinterpret_cast<const double2*>(&smd[D_H2 + 4 * q + 2]);
                    a0 += (double)wv.x * h0.x;
                    a1 += (double)wv.y * h0.y;
                    a2 += (double)wv.z * h1.x;
                    a3 += (double)wv.w * h1.y;
                }
                smd[D_FB + t] = tanh(b3t + (a0 + a2) + (a1 + a3));
            }
            __syncthreads();
            // wm[a][e] = sum_b CMAT[a][b] * F[b][e]
            {
                int a = t >> 6, e = t & 63;
                double a0 = 0.0, a1 = 0.0;
                #pragma unroll
                for (int bb = 0; bb < 8; bb += 2) {
                    a0 += smd[D_CMAT + a * 8 + bb]     * smd[D_FB + bb * 64 + e];
                    a1 += smd[D_CMAT + a * 8 + bb + 1] * smd[D_FB + (bb + 1) * 64 + e];
                }
                smd[D_WMT + a * 68 + e] = a0 + a1;
            }
            __syncthreads();
            // U1[a][r] = D1[r] * (W1 @ wm_a)[r] ; thread: a=t&7, r=t>>3 (+64)
            {
                int a = t & 7, r = t >> 3;
                double s00 = 0.0, s01 = 0.0, s10 = 0.0, s11 = 0.0;
                #pragma unroll
                for (int e2 = 0; e2 < 32; ++e2) {
                    float2 wa = W1P[e2 * 128 + r];
                    float2 wb = W1P[e2 * 128 + r + 64];
                    double2 wm = *reinterpret_cast<const double2*>(&smd[D_WMT + a * 68 + 2 * e2]);
                    s00 += (double)wa.x * wm.x;
                    s01 += (double)wa.y * wm.y;
                    s10 += (double)wb.x * wm.x;
                    s11 += (double)wb.y * wm.y;
                }
                smd[D_U1 + a * 132 + r]      = (s00 + s01) * smd[D_D1 + r];
                smd[D_U1 + a * 132 + r + 64] = (s10 + s11) * smd[D_D1 + r + 64];
            }
            __syncthreads();
            // U2[a][r] = D2[r] * (W2 @ U1_a)[r]
            {
                int a = t & 7, r = t >> 3;
                double s00 = 0.0, s01 = 0.0, s10 = 0.0, s11 = 0.0;
                #pragma unroll
                for (int c2 = 0; c2 < 64; ++c2) {
                    float2 wa = W2P[c2 * 128 + r];
                    float2 wb = W2P[c2 * 128 + r + 64];
                    double2 uv = *reinterpret_cast<const double2*>(&smd[D_U1 + a * 132 + 2 * c2]);
                    s00 += (double)wa.x * uv.x;
                    s01 += (double)wa.y * uv.y;
                    s10 += (double)wb.x * uv.x;
                    s11 += (double)wb.y * uv.y;
                }
                smd[D_U2 + a * 132 + r]      = (s00 + s01) * smd[D_D2 + r];
                smd[D_U2 + a * 132 + r + 64] = (s10 + s11) * smd[D_D2 + r + 64];
            }
            __syncthreads();
            // T3[t] = (1-F^2) * (W3[t,:] @ U2_a), a = t>>6
            {
                int a = t >> 6;
                double a0 = 0.0, a1 = 0.0, a2 = 0.0, a3 = 0.0;
                #pragma unroll
                for (int q = 0; q < 32; ++q) {
                    float4 wv = w3q[q];
                    double2 u0 = *reinterpret_cast<const double2*>(&smd[D_U2 + a * 132 + 4 * q]);
                    double2 u1 = *reinterpret_cast<const double2*>(&smd[D_U2 + a * 132 + 4 * q + 2]);
                    a0 += (double)wv.x * u0.x;
                    a1 += (double)wv.y * u0.y;
                    a2 += (double)wv.z * u1.x;
                    a3 += (double)wv.w * u1.y;
                }
                double F = smd[D_FB + t];
                smd[D_T3 + t] = (1.0 - F * F) * ((a0 + a2) + (a1 + a3));
            }
            __syncthreads();
            // combine + RK4 glue; fold next-window CMAT setup into stage 3
            if (t < 64) {
                double g = 0.0;
                #pragma unroll
                for (int a = 0; a < 8; ++a)
                    g += v[a] * smd[D_FB + a * 64 + t] + smd[D_T3 + a * 64 + t];
                double y = smd[D_YCUR + t];
                if (stage == 0)      { smd[D_KACC + t] = g;        smd[D_YBUF + t] = y + 0.5 * g; }
                else if (stage == 1) { smd[D_KACC + t] += 2.0 * g; smd[D_YBUF + t] = y + 0.5 * g; }
                else if (stage == 2) { smd[D_KACC + t] += 2.0 * g; smd[D_YBUF + t] = y + g; }
                else {
                    double yn = y + (smd[D_KACC + t] + g) * (1.0 / 6.0);
                    smd[D_YCUR + t] = yn;
                    smd[D_YBUF + t] = yn;
                    smd[D_HID + (w + 1) * 64 + t] = yn;
                }
            } else if (t < 128 && stage == 3 && w < 15) {
                int idx = t - 64;
                int a = idx >> 3, bb = idx & 7;
                double cv = 0.0;
                if (a != bb) {
                    int i = a < bb ? a : bb;
                    int j = a < bb ? bb : a;
                    int pidx = 7 * i - (i * (i - 1)) / 2 + (j - i - 1);
                    double vv = smd[D_VSIG + (w + 1) * 36 + 8 + pidx];
                    cv = (a > bb) ? vv : -vv;
                }
                smd[D_CMAT + idx] = cv;
            }
            __syncthreads();
        }
    }

    // ==== readout ====
    for (int idx = t; idx < 544; idx += NT) {
        int s = idx >> 5, o = idx & 31;
        double acc = (double)ro_b[o];
        const float* wr = ro_w + o * 64;
        const double* hr = &smd[D_HID + s * 64];
        #pragma unroll
        for (int d = 0; d < 64; ++d) acc += (double)wr[d] * hr[d];
        out[(size_t)b * 544 + idx] = (float)acc;
    }
}

extern "C" void kernel_launch(void* const* d_in, const int* in_sizes, int n_in,
                              void* d_out, int out_size, void* d_ws, size_t ws_size,
                              hipStream_t stream) {
    const float* x     = (const float*)d_in[0];
    const float* ic_w1 = (const float*)d_in[1];
    const float* ic_b1 = (const float*)d_in[2];
    const float* ic_w2 = (const float*)d_in[3];
    const float* ic_b2 = (const float*)d_in[4];
    const float* ic_w3 = (const float*)d_in[5];
    const float* ic_b3 = (const float*)d_in[6];
    const float* vf_w1 = (const float*)d_in[7];
    const float* vf_b1 = (const float*)d_in[8];
    const float* vf_w2 = (const float*)d_in[9];
    const float* vf_b2 = (const float*)d_in[10];
    const float* vf_w3 = (const float*)d_in[11];
    const float* vf_b3 = (const float*)d_in[12];
    const float* ro_w  = (const float*)d_in[13];
    const float* ro_b  = (const float*)d_in[14];
    float* out = (float*)d_out;

    int B = in_sizes[0] / (257 * 8);
    size_t shmem = (size_t)SMEM_BYTES;
    hipFuncSetAttribute(reinterpret_cast<const void*>(ncde_solve),
                        hipFuncAttributeMaxDynamicSharedMemorySize, (int)shmem);
    hipLaunchKernelGGL(ncde_solve, dim3(B), dim3(NT), shmem, stream,
                       x, ic_w1, ic_b1, ic_w2, ic_b2, ic_w3, ic_b3,
                       vf_w1, vf_b1, vf_w2, vf_b2, vf_w3, vf_b3, ro_w, ro_b, out);
}